// Round 10
// baseline (501.203 us; speedup 1.0000x reference)
//
#include <hip/hip_runtime.h>

#define N_NODES 50000
#define N_EDGES 600000
#define IN_CH 64
#define HID 128
#define N_GRAPHS 64
#define SCAN_BLOCKS 196   // ceil(N_NODES/256)

typedef __attribute__((ext_vector_type(8))) short bf16x8;
typedef __attribute__((ext_vector_type(4))) float f32x4;

// ---- bf16 helpers (manual, RNE) ----
__device__ __forceinline__ float bf2f(unsigned short u) {
    union { unsigned int i; float f; } v; v.i = ((unsigned int)u) << 16; return v.f;
}
__device__ __forceinline__ unsigned short f2bf(float f) {
    union { float f; unsigned int i; } v; v.f = f;
    unsigned int u = v.i;
    return (unsigned short)((u + 0x7FFFu + ((u >> 16) & 1u)) >> 16);
}
__device__ __forceinline__ float rowval(float f) { return f; }
__device__ __forceinline__ float rowval(unsigned short u) { return bf2f(u); }

template <bool B> struct RowType { using T = float; };
template <> struct RowType<true> { using T = unsigned short; };

// ===========================================================================
// CSR build (R8/R9-proven): counting-sort edges by dst; edata = {src,a0,a1,a2}.
// ===========================================================================
__global__ void hist_kernel(const int* __restrict__ ei, int* __restrict__ deg) {
    int e = blockIdx.x * blockDim.x + threadIdx.x;
    if (e < N_EDGES) atomicAdd(&deg[ei[N_EDGES + e]], 1);
}

__device__ __forceinline__ int block_incl_scan256(int v, int* sm, int t) {
    int val = v;
    sm[t] = val; __syncthreads();
    #pragma unroll
    for (int off = 1; off < 256; off <<= 1) {
        int n = (t >= off) ? sm[t - off] : 0;
        __syncthreads();
        val += n; sm[t] = val; __syncthreads();
    }
    return val;
}

__global__ void scan1_kernel(const int* __restrict__ deg, int* __restrict__ partials) {
    __shared__ int sm[256];
    int t = threadIdx.x;
    int i = blockIdx.x * 256 + t;
    int v = (i < N_NODES) ? deg[i] : 0;
    sm[t] = v; __syncthreads();
    for (int off = 128; off > 0; off >>= 1) {
        if (t < off) sm[t] += sm[t + off];
        __syncthreads();
    }
    if (t == 0) partials[blockIdx.x] = sm[0];
}

__global__ void scan2_kernel(int* __restrict__ partials) {
    __shared__ int sm[256];
    int t = threadIdx.x;
    int v = (t < SCAN_BLOCKS) ? partials[t] : 0;
    int incl = block_incl_scan256(v, sm, t);
    if (t < SCAN_BLOCKS) partials[t] = incl - v;
}

__global__ void scan3_kernel(const int* __restrict__ deg,
                             const int* __restrict__ partials,
                             int* __restrict__ rowptr,
                             int* __restrict__ cursor) {
    __shared__ int sm[256];
    int t = threadIdx.x;
    int i = blockIdx.x * 256 + t;
    int v = (i < N_NODES) ? deg[i] : 0;
    int incl = block_incl_scan256(v, sm, t);
    int excl = incl - v + partials[blockIdx.x];
    if (i < N_NODES) { rowptr[i] = excl; cursor[i] = excl; }
    if (blockIdx.x == 0 && t == 0) rowptr[N_NODES] = N_EDGES;
}

__global__ void scatter_kernel(const int* __restrict__ ei,
                               const float* __restrict__ ea,
                               int* __restrict__ cursor,
                               int4* __restrict__ edata) {
    int e = blockIdx.x * blockDim.x + threadIdx.x;
    if (e < N_EDGES) {
        int dst = ei[N_EDGES + e];
        int pos = atomicAdd(&cursor[dst], 1);
        edata[pos] = make_int4(ei[e],
                               __float_as_int(ea[3 * e]),
                               __float_as_int(ea[3 * e + 1]),
                               __float_as_int(ea[3 * e + 2]));
    }
}

// transpose + bf16: wT[n*Kdim + k] = w[k*Ndim + n]  (R6 correctness-proven)
__global__ void tw_kernel(const float* __restrict__ w, unsigned short* __restrict__ wT,
                          int Kdim, int Ndim) {
    int i = blockIdx.x * blockDim.x + threadIdx.x;
    if (i < Kdim * Ndim) {
        int k = i / Ndim, n = i % Ndim;
        wT[n * Kdim + k] = f2bf(w[k * Ndim + n]);
    }
}

// ===========================================================================
// Fused GINE layer: gather = R9 byte-identical (only the LDS store is f2bf);
// MLP = R6's correctness-proven MFMA block, 2 waves x 4 col-tiles each.
// 128 threads, NPB=8 nodes/block. Fragment rows 8-15 are garbage; MFMA rows
// are independent (D[m][n]=sum_k A[m][k]B[k][n]) so they never contaminate
// rows 0-7; epilogue guards q<2.
// [R8 lesson: scalar-MLP vectorization costs occupancy; MFMA instead.]
// ===========================================================================
template <int K, bool XBF, bool POOL>
__global__ void fused_layer(const void* __restrict__ xinv,
                            const int4* __restrict__ edata,
                            const int* __restrict__ rowptr,
                            const float* __restrict__ elw,   // [3, K] f32
                            const float* __restrict__ elb,   // [K] f32
                            const unsigned short* __restrict__ waT,  // bf16 [HID, K]
                            const float* __restrict__ ba,
                            const unsigned short* __restrict__ wbT,  // bf16 [HID, HID]
                            const float* __restrict__ bb,
                            void* __restrict__ outv,         // bf16 h [N,HID] or f32 psum
                            const int* __restrict__ batch) {
    using RowT = typename RowType<XBF>::T;
    const RowT* __restrict__ xin = (const RowT*)xinv;
    constexpr int NPB = 8;
    constexpr int SSTR = (K == 128) ? 136 : 80;   // shorts; x2B = 16B-multiple
    constexpr int HSTR = 136;
    __shared__ __align__(16) unsigned short sInB[16 * SSTR];
    __shared__ __align__(16) unsigned short sHidB[16 * HSTR];
    const int t = threadIdx.x;  // 0..127
    const int w = t >> 6, l = t & 63;
    const int node0 = blockIdx.x * NPB;

    // ---- aggregation (gather over CSR, 8 rows in flight) — R9-identical ----
    {
        const int c = (K == 128) ? t : (t & 63);
        const int half = (K == 128) ? 0 : (t >> 6);
        const int istep = (K == 128) ? 1 : 2;
        const float w0 = elw[c], w1 = elw[K + c], w2 = elw[2 * K + c], eb = elb[c];

        auto term = [&](int4 e, RowT row) -> float {
            float ev = __int_as_float(e.y) * w0 + __int_as_float(e.z) * w1 +
                       __int_as_float(e.w) * w2 + eb;
            float m = rowval(row) + ev;
            return m > 0.f ? m : 0.f;
        };

        for (int i = 0; i < NPB; i += istep) {
            int node = node0 + i + half;
            float acc = rowval(xin[(size_t)node * K + c]);
            int jb = rowptr[node], je = rowptr[node + 1];
            int j = jb;
            for (; j + 8 <= je; j += 8) {
                int4 e0 = edata[j],     e1 = edata[j + 1], e2 = edata[j + 2], e3 = edata[j + 3];
                int4 e4 = edata[j + 4], e5 = edata[j + 5], e6 = edata[j + 6], e7 = edata[j + 7];
                RowT r0 = xin[(size_t)e0.x * K + c];
                RowT r1 = xin[(size_t)e1.x * K + c];
                RowT r2 = xin[(size_t)e2.x * K + c];
                RowT r3 = xin[(size_t)e3.x * K + c];
                RowT r4 = xin[(size_t)e4.x * K + c];
                RowT r5 = xin[(size_t)e5.x * K + c];
                RowT r6 = xin[(size_t)e6.x * K + c];
                RowT r7 = xin[(size_t)e7.x * K + c];
                acc += term(e0, r0) + term(e1, r1) + term(e2, r2) + term(e3, r3)
                     + term(e4, r4) + term(e5, r5) + term(e6, r6) + term(e7, r7);
            }
            for (; j + 4 <= je; j += 4) {
                int4 e0 = edata[j], e1 = edata[j + 1], e2 = edata[j + 2], e3 = edata[j + 3];
                RowT r0 = xin[(size_t)e0.x * K + c];
                RowT r1 = xin[(size_t)e1.x * K + c];
                RowT r2 = xin[(size_t)e2.x * K + c];
                RowT r3 = xin[(size_t)e3.x * K + c];
                acc += term(e0, r0) + term(e1, r1) + term(e2, r2) + term(e3, r3);
            }
            for (; j < je; j++) {
                int4 e0 = edata[j];
                acc += term(e0, xin[(size_t)e0.x * K + c]);
            }
            sInB[(i + half) * SSTR + c] = f2bf(acc);
        }
    }
    __syncthreads();

    // ---- MFMA MLP (R6-proven fragments) ----
    const int i16 = l & 15, q = l >> 4;

    // layer A: [16 x K] @ waT -> this wave's 64 cols (4 tiles of 16)
    bf16x8 aA[K / 32];
    #pragma unroll
    for (int s = 0; s < K / 32; s++)
        aA[s] = *(const bf16x8*)&sInB[i16 * SSTR + s * 32 + q * 8];
    f32x4 accA[4];
    #pragma unroll
    for (int ct = 0; ct < 4; ct++) {
        int col = w * 64 + ct * 16 + i16;
        float bv = ba[col];
        accA[ct] = (f32x4){bv, bv, bv, bv};
        #pragma unroll
        for (int s = 0; s < K / 32; s++) {
            bf16x8 b = *(const bf16x8*)&waT[(size_t)col * K + s * 32 + q * 8];
            accA[ct] = __builtin_amdgcn_mfma_f32_16x16x32_bf16(aA[s], b, accA[ct], 0, 0, 0);
        }
    }
    // relu -> sHid (bf16). D layout: col = i16, row = q*4+r.
    #pragma unroll
    for (int ct = 0; ct < 4; ct++) {
        #pragma unroll
        for (int r = 0; r < 4; r++) {
            int row = q * 4 + r;
            float v = accA[ct][r] > 0.f ? accA[ct][r] : 0.f;
            sHidB[row * HSTR + w * 64 + ct * 16 + i16] = f2bf(v);
        }
    }
    __syncthreads();

    // layer B: [16 x 128] @ wbT
    bf16x8 aB[4];
    #pragma unroll
    for (int s = 0; s < 4; s++)
        aB[s] = *(const bf16x8*)&sHidB[i16 * HSTR + s * 32 + q * 8];
    f32x4 accB[4];
    #pragma unroll
    for (int ct = 0; ct < 4; ct++) {
        int col = w * 64 + ct * 16 + i16;
        float bv = bb[col];
        accB[ct] = (f32x4){bv, bv, bv, bv};
        #pragma unroll
        for (int s = 0; s < 4; s++) {
            bf16x8 b = *(const bf16x8*)&wbT[(size_t)col * HID + s * 32 + q * 8];
            accB[ct] = __builtin_amdgcn_mfma_f32_16x16x32_bf16(aB[s], b, accB[ct], 0, 0, 0);
        }
    }
    // epilogue: rows 0..7 only (q<2); outer relu
    if (q < 2) {
        #pragma unroll
        for (int ct = 0; ct < 4; ct++) {
            int col = w * 64 + ct * 16 + i16;
            #pragma unroll
            for (int r = 0; r < 4; r++) {
                int row = q * 4 + r;
                int node = node0 + row;
                float v = accB[ct][r] > 0.f ? accB[ct][r] : 0.f;
                if (POOL) {
                    atomicAdd(&((float*)outv)[batch[node] * HID + col], v);
                } else {
                    ((unsigned short*)outv)[(size_t)node * HID + col] = f2bf(v);
                }
            }
        }
    }
}

// ---------------------------------------------------------------------------
// Pool mean: batch is SORTED -> count[g] by binary search (wave-uniform).
// ---------------------------------------------------------------------------
__global__ void pool_div_kernel(const float* __restrict__ sums,
                                const int* __restrict__ batch,
                                float* __restrict__ out) {
    int i = blockIdx.x * blockDim.x + threadIdx.x;
    if (i >= N_GRAPHS * HID) return;
    int g = i / HID;
    int lo = 0, hi = N_NODES;
    while (lo < hi) { int mid = (lo + hi) >> 1; if (batch[mid] < g) lo = mid + 1; else hi = mid; }
    int start = lo;
    lo = 0; hi = N_NODES;
    while (lo < hi) { int mid = (lo + hi) >> 1; if (batch[mid] <= g) lo = mid + 1; else hi = mid; }
    float c = (float)(lo - start);
    out[i] = sums[i] / (c > 1.0f ? c : 1.0f);
}

extern "C" void kernel_launch(void* const* d_in, const int* in_sizes, int n_in,
                              void* d_out, int out_size, void* d_ws, size_t ws_size,
                              hipStream_t stream) {
    const float* x    = (const float*)d_in[0];
    const int*   ei   = (const int*)d_in[1];
    const float* ea   = (const float*)d_in[2];
    const int*   batch= (const int*)d_in[3];
    const float* el1w = (const float*)d_in[4];
    const float* el1b = (const float*)d_in[5];
    const float* w1a  = (const float*)d_in[6];
    const float* b1a  = (const float*)d_in[7];
    const float* w1b  = (const float*)d_in[8];
    const float* b1b  = (const float*)d_in[9];
    const float* el2w = (const float*)d_in[10];
    const float* el2b = (const float*)d_in[11];
    const float* w2a  = (const float*)d_in[12];
    const float* b2a  = (const float*)d_in[13];
    const float* w2b  = (const float*)d_in[14];
    const float* b2b  = (const float*)d_in[15];
    float* out = (float*)d_out;

    // workspace layout (16B-aligned sections)
    int4*  edata    = (int4*)d_ws;                      // [E] {src,a0,a1,a2}
    float* psum     = (float*)(edata + N_EDGES);        // [G*HID] 8192 f32
    int*   deg      = (int*)(psum + N_GRAPHS * HID);    // [N]
    int*   cursor   = deg + N_NODES;                    // [N]
    int*   rowptr   = cursor + N_NODES;                 // [N+1]
    int*   partials = rowptr + N_NODES + 1;             // [256]
    // ints so far: 8192+50000+50000+50001+256 = 158449; pad to 158452 (16B mult)
    unsigned short* hbf  = (unsigned short*)((char*)psum + (size_t)158452 * 4);  // bf16 [N,HID]
    unsigned short* waT1 = hbf + (size_t)N_NODES * HID;  // bf16 [128, 64]
    unsigned short* wbT1 = waT1 + HID * IN_CH;           // bf16 [128, 128]
    unsigned short* waT2 = wbT1 + HID * HID;             // bf16 [128, 128]
    unsigned short* wbT2 = waT2 + HID * HID;             // bf16 [128, 128]

    // ---- prep: CSR build (parallel scan) + weight transpose ----
    hipMemsetAsync(deg, 0, N_NODES * sizeof(int), stream);
    hist_kernel<<<(N_EDGES + 255) / 256, 256, 0, stream>>>(ei, deg);
    tw_kernel<<<(IN_CH * HID + 255) / 256, 256, 0, stream>>>(w1a, waT1, IN_CH, HID);
    tw_kernel<<<(HID * HID + 255) / 256, 256, 0, stream>>>(w1b, wbT1, HID, HID);
    tw_kernel<<<(HID * HID + 255) / 256, 256, 0, stream>>>(w2a, waT2, HID, HID);
    tw_kernel<<<(HID * HID + 255) / 256, 256, 0, stream>>>(w2b, wbT2, HID, HID);
    scan1_kernel<<<SCAN_BLOCKS, 256, 0, stream>>>(deg, partials);
    scan2_kernel<<<1, 256, 0, stream>>>(partials);
    scan3_kernel<<<SCAN_BLOCKS, 256, 0, stream>>>(deg, partials, rowptr, cursor);
    scatter_kernel<<<(N_EDGES + 255) / 256, 256, 0, stream>>>(ei, ea, cursor, edata);

    // ---- layer 1: f32 gather + MFMA MLP, h out as bf16 ----
    fused_layer<IN_CH, false, false><<<N_NODES / 8, 128, 0, stream>>>(
        x, edata, rowptr, el1w, el1b, waT1, b1a, wbT1, b1b, hbf, nullptr);

    // ---- layer 2: bf16 gather + MFMA MLP + pool atomics ----
    hipMemsetAsync(psum, 0, N_GRAPHS * HID * sizeof(float), stream);
    fused_layer<HID, true, true><<<N_NODES / 8, 128, 0, stream>>>(
        hbf, edata, rowptr, el2w, el2b, waT2, b2a, wbT2, b2b, psum, batch);

    // ---- mean (count via binary search on sorted batch) ----
    pool_div_kernel<<<(N_GRAPHS * HID + 255) / 256, 256, 0, stream>>>(psum, batch, out);
}